// Round 2
// baseline (837.021 us; speedup 1.0000x reference)
//
#include <hip/hip_runtime.h>
#include <hip/hip_bf16.h>
#include <math.h>

// ---------------- constants (problem instance is fixed) ----------------
#define BATCH 4
#define NFRM  4
#define STOK  768
#define TIMG  3072   // NFRM*STOK
#define SEQ   3120   // TIMG + 48
#define DM    2048
#define NH    16
#define HDIM  128
#define MTOK  12288  // BATCH*TIMG

typedef __attribute__((ext_vector_type(8))) short short8;
typedef __attribute__((ext_vector_type(4))) float f32x4;

__device__ __forceinline__ unsigned short f2bf(float f) {
  unsigned u = __float_as_uint(f);
  u += 0x7FFF + ((u >> 16) & 1);
  return (unsigned short)(u >> 16);
}
__device__ __forceinline__ float bf2f(unsigned short s) {
  return __uint_as_float(((unsigned)s) << 16);
}

__device__ __forceinline__ void gload_lds16(const void* g, void* l) {
  __builtin_amdgcn_global_load_lds(
      (const __attribute__((address_space(1))) void*)g,
      (__attribute__((address_space(3))) void*)l,
      16, 0, 0);
}

// ---------------- pos-enc table: enc[n*DM + d] ----------------
__global__ void k_enc(const float* __restrict__ fi, float* __restrict__ enc) {
  int i = blockIdx.x * 256 + threadIdx.x;  // 0..8191
  if (i >= NFRM * DM) return;
  int n = i >> 11;
  int d = i & (DM - 1);
  int dd = d & 1023;
  float fraction = dd * (1.0f / 1023.0f);
  float period = 0.01f * powf(1000.0f, fraction);
  float sc = 6.283185307179586f / period;
  float x = (n * fi[0]) * sc;
  enc[i] = (d < 1024) ? sinf(x) : cosf(x);
}

// ---------------- weights fp32 -> bf16 (Wq,Wk,Wv concat; Wo separate) ----------------
__global__ void k_wconv(const float4* __restrict__ Wq, const float4* __restrict__ Wk,
                        const float4* __restrict__ Wv, const float4* __restrict__ Wo,
                        unsigned short* __restrict__ wqkv, unsigned short* __restrict__ wo) {
  int id = blockIdx.x * 256 + threadIdx.x;  // 0 .. 4*1048576-1
  int mat = id >> 20;                       // 1048576 float4 per 2048x2048 matrix
  int j = id & 1048575;
  const float4* src = (mat == 0) ? Wq : (mat == 1) ? Wk : (mat == 2) ? Wv : Wo;
  float4 v = src[j];
  ushort4 o4;
  o4.x = f2bf(v.x); o4.y = f2bf(v.y); o4.z = f2bf(v.z); o4.w = f2bf(v.w);
  unsigned short* dst = (mat < 3) ? (wqkv + (size_t)mat * 4194304) : wo;
  *(ushort4*)&dst[(size_t)j * 4] = o4;
}

// ---------------- LayerNorm + pos-enc -> X bf16 (token order b,n,s) ----------------
__global__ __launch_bounds__(256)
void k_ln(const float* __restrict__ hid, const float* __restrict__ gamma,
          const float* __restrict__ beta, const float* __restrict__ enc,
          unsigned short* __restrict__ X) {
  int token = blockIdx.x;            // 0..12287, = b*TIMG + t
  int b = token / TIMG;
  int t = token - b * TIMG;
  int n = t / STOK;
  const float* row = hid + (size_t)(b * SEQ + t) * DM;
  int tid = threadIdx.x;

  float xv[8];
  *(float4*)&xv[0] = *(const float4*)&row[tid * 8];
  *(float4*)&xv[4] = *(const float4*)&row[tid * 8 + 4];

  float s = 0.f, ss = 0.f;
#pragma unroll
  for (int j = 0; j < 8; ++j) { s += xv[j]; ss += xv[j] * xv[j]; }
#pragma unroll
  for (int mask = 32; mask >= 1; mask >>= 1) {
    s += __shfl_xor(s, mask);
    ss += __shfl_xor(ss, mask);
  }
  __shared__ float ps[4], pss[4];
  int lane = tid & 63, wid = tid >> 6;
  if (lane == 0) { ps[wid] = s; pss[wid] = ss; }
  __syncthreads();
  s = ps[0] + ps[1] + ps[2] + ps[3];
  ss = pss[0] + pss[1] + pss[2] + pss[3];

  float mean = s * (1.0f / DM);
  float var = ss * (1.0f / DM) - mean * mean;
  float inv = rsqrtf(var + 1e-5f);

  float gv[8], bv[8], ev[8];
  *(float4*)&gv[0] = *(const float4*)&gamma[tid * 8];
  *(float4*)&gv[4] = *(const float4*)&gamma[tid * 8 + 4];
  *(float4*)&bv[0] = *(const float4*)&beta[tid * 8];
  *(float4*)&bv[4] = *(const float4*)&beta[tid * 8 + 4];
  *(float4*)&ev[0] = *(const float4*)&enc[n * DM + tid * 8];
  *(float4*)&ev[4] = *(const float4*)&enc[n * DM + tid * 8 + 4];

  short8 outv;
#pragma unroll
  for (int j = 0; j < 8; ++j) {
    float y = (xv[j] - mean) * inv * gv[j] + bv[j] + ev[j];
    outv[j] = (short)f2bf(y);
  }
  *(short8*)&X[(size_t)token * DM + tid * 8] = outv;
}

// ---------------- GEMM: C[M,N] = A[M,K] * B[N,K]^T (bf16 in, fp32 acc) ----------------
// EPI 0: write bf16 C (ld = N).  EPI 1: fp32 out with residual add + seq-3120 scatter.
template <int EPI>
__global__ __launch_bounds__(256)
void gemm_bt(const unsigned short* __restrict__ A, const unsigned short* __restrict__ B,
             unsigned short* __restrict__ Cb, float* __restrict__ Cf,
             const float* __restrict__ resid, int M, int N, int K) {
  __shared__ unsigned short ldsA[128 * 32];
  __shared__ unsigned short ldsB[128 * 32];
  const int tid = threadIdx.x;
  const int lane = tid & 63;
  const int wid = tid >> 6;
  const int tm = blockIdx.y * 128;
  const int tn = blockIdx.x * 128;
  const int l16 = lane & 15;
  const int kq = lane >> 4;          // 0..3
  const int wr = (wid >> 1) * 64;
  const int wc = (wid & 1) * 64;

  f32x4 zero = {0.f, 0.f, 0.f, 0.f};
  f32x4 acc[4][4];
#pragma unroll
  for (int i = 0; i < 4; ++i)
#pragma unroll
    for (int j = 0; j < 4; ++j) acc[i][j] = zero;

  // staging: 512 16B-chunks per tile; chunk c -> row c>>2, 16B-seg c&3
  const int c0 = wid * 64 + lane;        // 0..255
  const int r0 = c0 >> 2, s0 = c0 & 3;
  const int c1 = 256 + c0;
  const int r1 = c1 >> 2, s1 = c1 & 3;

  const unsigned short* ga0 = A + (size_t)(tm + r0) * K + s0 * 8;
  const unsigned short* ga1 = A + (size_t)(tm + r1) * K + s1 * 8;
  const unsigned short* gb0 = B + (size_t)(tn + r0) * K + s0 * 8;
  const unsigned short* gb1 = B + (size_t)(tn + r1) * K + s1 * 8;
  char* la0 = (char*)ldsA + (wid * 64) * 16;
  char* la1 = (char*)ldsA + (256 + wid * 64) * 16;
  char* lb0 = (char*)ldsB + (wid * 64) * 16;
  char* lb1 = (char*)ldsB + (256 + wid * 64) * 16;

  for (int k0 = 0; k0 < K; k0 += 32) {
    __syncthreads();
    gload_lds16(ga0 + k0, la0);
    gload_lds16(ga1 + k0, la1);
    gload_lds16(gb0 + k0, lb0);
    gload_lds16(gb1 + k0, lb1);
    __syncthreads();

    short8 a[4], b[4];
#pragma unroll
    for (int mi = 0; mi < 4; ++mi)
      a[mi] = *(const short8*)&ldsA[(wr + mi * 16 + l16) * 32 + kq * 8];
#pragma unroll
    for (int ni = 0; ni < 4; ++ni)
      b[ni] = *(const short8*)&ldsB[(wc + ni * 16 + l16) * 32 + kq * 8];
#pragma unroll
    for (int mi = 0; mi < 4; ++mi)
#pragma unroll
      for (int ni = 0; ni < 4; ++ni)
        acc[mi][ni] = __builtin_amdgcn_mfma_f32_16x16x32_bf16(a[mi], b[ni], acc[mi][ni], 0, 0, 0);
  }

#pragma unroll
  for (int mi = 0; mi < 4; ++mi) {
#pragma unroll
    for (int ni = 0; ni < 4; ++ni) {
      int row0 = tm + wr + mi * 16 + kq * 4;
      int colg = tn + wc + ni * 16 + l16;
#pragma unroll
      for (int r = 0; r < 4; ++r) {
        int row = row0 + r;
        float val = acc[mi][ni][r];
        if (EPI == 0) {
          Cb[(size_t)row * N + colg] = f2bf(val);
        } else {
          int bb = row / TIMG;
          int t = row - bb * TIMG;
          size_t o = (size_t)(bb * SEQ + t) * DM + colg;
          Cf[o] = resid[o] + val;
        }
      }
    }
  }
}

// ---------------- attention over frames: per (b,s), 16 thr/head ----------------
__global__ __launch_bounds__(256)
void k_attn(const unsigned short* __restrict__ QKV, unsigned short* __restrict__ AOUT) {
  int bs = blockIdx.x;               // 0..3071
  int b = bs / STOK;
  int s = bs - b * STOK;
  int tid = threadIdx.x;
  int h = tid >> 4;
  int part = tid & 15;
  int col = h * HDIM + part * 8;

  float q[4][8], k[4][8], v[4][8];
#pragma unroll
  for (int n = 0; n < 4; ++n) {
    size_t base = (size_t)(b * TIMG + n * STOK + s) * 6144;
    short8 qa = *(const short8*)&QKV[base + col];
    short8 ka = *(const short8*)&QKV[base + 2048 + col];
    short8 va = *(const short8*)&QKV[base + 4096 + col];
#pragma unroll
    for (int j = 0; j < 8; ++j) {
      q[n][j] = bf2f((unsigned short)qa[j]);
      k[n][j] = bf2f((unsigned short)ka[j]);
      v[n][j] = bf2f((unsigned short)va[j]);
    }
  }

  float sc[4][4];
#pragma unroll
  for (int n = 0; n < 4; ++n)
#pragma unroll
    for (int m = 0; m < 4; ++m) {
      float a = 0.f;
#pragma unroll
      for (int j = 0; j < 8; ++j) a += q[n][j] * k[m][j];
#pragma unroll
      for (int mask = 8; mask >= 1; mask >>= 1) a += __shfl_xor(a, mask);
      sc[n][m] = a * 0.08838834764831845f;  // 1/sqrt(128)
    }

  float p[4][4];
#pragma unroll
  for (int n = 0; n < 4; ++n) {
    float mx = fmaxf(fmaxf(sc[n][0], sc[n][1]), fmaxf(sc[n][2], sc[n][3]));
    float sum = 0.f;
#pragma unroll
    for (int m = 0; m < 4; ++m) { p[n][m] = expf(sc[n][m] - mx); sum += p[n][m]; }
    float inv = 1.f / sum;
#pragma unroll
    for (int m = 0; m < 4; ++m) p[n][m] *= inv;
  }

#pragma unroll
  for (int n = 0; n < 4; ++n) {
    float o[8];
#pragma unroll
    for (int j = 0; j < 8; ++j) o[j] = 0.f;
#pragma unroll
    for (int m = 0; m < 4; ++m)
#pragma unroll
      for (int j = 0; j < 8; ++j) o[j] += p[n][m] * v[m][j];
    short8 ov;
#pragma unroll
    for (int j = 0; j < 8; ++j) ov[j] = (short)f2bf(o[j]);
    size_t obase = (size_t)(b * TIMG + n * STOK + s) * DM + col;
    *(short8*)&AOUT[obase] = ov;
  }
}

// ---------------- passthrough for the 48 "other" tokens per batch ----------------
__global__ void k_other(const float4* __restrict__ hid, float4* __restrict__ out) {
  int i = blockIdx.x * 256 + threadIdx.x;  // 0..98303
  int b = i / 24576;                       // 48*2048/4 float4 per batch
  int r = i - b * 24576;
  size_t off = ((size_t)(b * SEQ + TIMG) * DM) / 4 + r;
  out[off] = hid[off];
}

// ---------------- launcher ----------------
extern "C" void kernel_launch(void* const* d_in, const int* in_sizes, int n_in,
                              void* d_out, int out_size, void* d_ws, size_t ws_size,
                              hipStream_t stream) {
  const float* hid   = (const float*)d_in[0];
  const float* Wq    = (const float*)d_in[1];
  const float* Wk    = (const float*)d_in[2];
  const float* Wv    = (const float*)d_in[3];
  const float* Wo    = (const float*)d_in[4];
  const float* gamma = (const float*)d_in[5];
  const float* beta  = (const float*)d_in[6];
  const float* fint  = (const float*)d_in[9];
  float* out = (float*)d_out;

  char* ws = (char*)d_ws;
  float*          enc  = (float*)(ws + 0);                 //    32 KB
  unsigned short* wqkv = (unsigned short*)(ws + 32768);     //  24 MB (6144x2048 bf16)
  unsigned short* wo   = (unsigned short*)(ws + 25198592);  //   8 MB
  unsigned short* X    = (unsigned short*)(ws + 33587200);  //  48 MB (12288x2048 bf16)
  unsigned short* QKV  = (unsigned short*)(ws + 83918848);  // 144 MB (12288x6144 bf16)
  unsigned short* aout = X;  // reuse X's space after GEMM1 (stream-ordered)

  k_enc<<<32, 256, 0, stream>>>(fint, enc);
  k_wconv<<<16384, 256, 0, stream>>>((const float4*)Wq, (const float4*)Wk,
                                     (const float4*)Wv, (const float4*)Wo, wqkv, wo);
  k_ln<<<MTOK, 256, 0, stream>>>(hid, gamma, beta, enc, X);
  gemm_bt<0><<<dim3(48, 96), 256, 0, stream>>>(X, wqkv, QKV, nullptr, nullptr,
                                               MTOK, 6144, DM);
  k_attn<<<BATCH * STOK, 256, 0, stream>>>(QKV, aout);
  gemm_bt<1><<<dim3(16, 96), 256, 0, stream>>>(aout, wo, nullptr, out, hid,
                                               MTOK, DM, DM);
  k_other<<<384, 256, 0, stream>>>((const float4*)hid, (float4*)out);
}

// Round 3
// 705.686 us; speedup vs baseline: 1.1861x; 1.1861x over previous
//
#include <hip/hip_runtime.h>
#include <hip/hip_bf16.h>
#include <math.h>

// ---------------- constants (problem instance is fixed) ----------------
#define BATCH 4
#define NFRM  4
#define STOK  768
#define TIMG  3072   // NFRM*STOK
#define SEQ   3120   // TIMG + 48
#define DM    2048
#define NH    16
#define HDIM  128
#define MTOK  12288  // BATCH*TIMG

typedef __attribute__((ext_vector_type(8))) short short8;
typedef __attribute__((ext_vector_type(4))) float f32x4;

__device__ __forceinline__ unsigned short f2bf(float f) {
  unsigned u = __float_as_uint(f);
  u += 0x7FFF + ((u >> 16) & 1);
  return (unsigned short)(u >> 16);
}
__device__ __forceinline__ float bf2f(unsigned short s) {
  return __uint_as_float(((unsigned)s) << 16);
}

__device__ __forceinline__ void gload_lds16(const void* g, void* l) {
  __builtin_amdgcn_global_load_lds(
      (const __attribute__((address_space(1))) void*)g,
      (__attribute__((address_space(3))) void*)l,
      16, 0, 0);
}

__device__ __forceinline__ void barrier_fenced() {
  asm volatile("" ::: "memory");
  __builtin_amdgcn_s_barrier();
  asm volatile("" ::: "memory");
}

// ---------------- pos-enc table: enc[n*DM + d] ----------------
__global__ void k_enc(const float* __restrict__ fi, float* __restrict__ enc) {
  int i = blockIdx.x * 256 + threadIdx.x;  // 0..8191
  if (i >= NFRM * DM) return;
  int n = i >> 11;
  int d = i & (DM - 1);
  int dd = d & 1023;
  float fraction = dd * (1.0f / 1023.0f);
  float period = 0.01f * powf(1000.0f, fraction);
  float sc = 6.283185307179586f / period;
  float x = (n * fi[0]) * sc;
  enc[i] = (d < 1024) ? sinf(x) : cosf(x);
}

// ---------------- weights fp32 -> bf16 (Wq,Wk,Wv concat; Wo separate) ----------------
__global__ void k_wconv(const float4* __restrict__ Wq, const float4* __restrict__ Wk,
                        const float4* __restrict__ Wv, const float4* __restrict__ Wo,
                        unsigned short* __restrict__ wqkv, unsigned short* __restrict__ wo) {
  int id = blockIdx.x * 256 + threadIdx.x;  // 0 .. 4*1048576-1
  int mat = id >> 20;                       // 1048576 float4 per 2048x2048 matrix
  int j = id & 1048575;
  const float4* src = (mat == 0) ? Wq : (mat == 1) ? Wk : (mat == 2) ? Wv : Wo;
  float4 v = src[j];
  ushort4 o4;
  o4.x = f2bf(v.x); o4.y = f2bf(v.y); o4.z = f2bf(v.z); o4.w = f2bf(v.w);
  unsigned short* dst = (mat < 3) ? (wqkv + (size_t)mat * 4194304) : wo;
  *(ushort4*)&dst[(size_t)j * 4] = o4;
}

// ---------------- LayerNorm + pos-enc -> X bf16 (token order b,n,s) ----------------
__global__ __launch_bounds__(256)
void k_ln(const float* __restrict__ hid, const float* __restrict__ gamma,
          const float* __restrict__ beta, const float* __restrict__ enc,
          unsigned short* __restrict__ X) {
  int token = blockIdx.x;            // 0..12287, = b*TIMG + t
  int b = token / TIMG;
  int t = token - b * TIMG;
  int n = t / STOK;
  const float* row = hid + (size_t)(b * SEQ + t) * DM;
  int tid = threadIdx.x;

  float xv[8];
  *(float4*)&xv[0] = *(const float4*)&row[tid * 8];
  *(float4*)&xv[4] = *(const float4*)&row[tid * 8 + 4];

  float s = 0.f, ss = 0.f;
#pragma unroll
  for (int j = 0; j < 8; ++j) { s += xv[j]; ss += xv[j] * xv[j]; }
#pragma unroll
  for (int mask = 32; mask >= 1; mask >>= 1) {
    s += __shfl_xor(s, mask);
    ss += __shfl_xor(ss, mask);
  }
  __shared__ float ps[4], pss[4];
  int lane = tid & 63, wid = tid >> 6;
  if (lane == 0) { ps[wid] = s; pss[wid] = ss; }
  __syncthreads();
  s = ps[0] + ps[1] + ps[2] + ps[3];
  ss = pss[0] + pss[1] + pss[2] + pss[3];

  float mean = s * (1.0f / DM);
  float var = ss * (1.0f / DM) - mean * mean;
  float inv = rsqrtf(var + 1e-5f);

  float gv[8], bv[8], ev[8];
  *(float4*)&gv[0] = *(const float4*)&gamma[tid * 8];
  *(float4*)&gv[4] = *(const float4*)&gamma[tid * 8 + 4];
  *(float4*)&bv[0] = *(const float4*)&beta[tid * 8];
  *(float4*)&bv[4] = *(const float4*)&beta[tid * 8 + 4];
  *(float4*)&ev[0] = *(const float4*)&enc[n * DM + tid * 8];
  *(float4*)&ev[4] = *(const float4*)&enc[n * DM + tid * 8 + 4];

  short8 outv;
#pragma unroll
  for (int j = 0; j < 8; ++j) {
    float y = (xv[j] - mean) * inv * gv[j] + bv[j] + ev[j];
    outv[j] = (short)f2bf(y);
  }
  *(short8*)&X[(size_t)token * DM + tid * 8] = outv;
}

// ---------------- 256x256 deep-pipelined GEMM: C[M,N] = A[M,K] * B[N,K]^T ----------------
// 512 threads = 8 waves (2m x 4n). BK=64. LDS 128KB double-buffered.
// XOR swizzle slot^=(row&7) at 16B granularity, pre-swizzled global src for
// global_load_lds (linear dest) + swizzled ds_read. Counted vmcnt(8): next
// K-tile's 8 loads stay in flight across the whole compute phase.
// EPI 0: write bf16 C (ld=N).  EPI 1: fp32 out with residual add + seq scatter.
template <int EPI>
__global__ __launch_bounds__(512, 2)
void gemm256(const unsigned short* __restrict__ A, const unsigned short* __restrict__ B,
             unsigned short* __restrict__ Cb, float* __restrict__ Cf,
             const float* __restrict__ resid, int M, int N, int K, int nbx) {
  __shared__ char lds[131072];  // [buf][A 32KB | B 32KB]

  const int nwg = gridDim.x;            // multiple of 8 by construction
  const int q = nwg >> 3;
  const int bid = blockIdx.x;
  const int swz = (bid & 7) * q + (bid >> 3);   // XCD-aware swizzle (bijective)
  const int by = swz / nbx;
  const int bx = swz - by * nbx;
  const int tm = by * 256, tn = bx * 256;

  const int tid = threadIdx.x;
  const int lane = tid & 63;
  const int wid = tid >> 6;
  const int wm = wid >> 2;              // 0..1
  const int wn = wid & 3;               // 0..3
  const int l16 = lane & 15;
  const int kq = lane >> 4;             // 0..3

  // --- precomputed staging addresses (loop-invariant except k0/buf) ---
  const int srow = tid >> 3;            // 0..63 within each 64-row issue
  const int sslot = tid & 7;
  const unsigned short* gA[4];
  const unsigned short* gB[4];
#pragma unroll
  for (int i = 0; i < 4; ++i) {
    int row = i * 64 + srow;
    int lslot = sslot ^ (row & 7);      // inverse-swizzled source slot
    gA[i] = A + (size_t)(tm + row) * K + lslot * 8;
    gB[i] = B + (size_t)(tn + row) * K + lslot * 8;
  }

  f32x4 acc[8][4];
#pragma unroll
  for (int i = 0; i < 8; ++i)
#pragma unroll
    for (int j = 0; j < 4; ++j) acc[i][j] = (f32x4){0.f, 0.f, 0.f, 0.f};

  auto STAGE = [&](int k0, int buf) {
    char* base = lds + buf * 65536 + wid * 1024;   // wave-uniform dest base
#pragma unroll
    for (int i = 0; i < 4; ++i) gload_lds16(gA[i] + k0, base + i * 8192);
#pragma unroll
    for (int i = 0; i < 4; ++i) gload_lds16(gB[i] + k0, base + 32768 + i * 8192);
  };

  auto COMPUTE = [&](int buf) {
    const char* pa = lds + buf * 65536;
    const char* pb = pa + 32768;
    short8 breg[4][2];
#pragma unroll
    for (int ni = 0; ni < 4; ++ni)
#pragma unroll
      for (int ks = 0; ks < 2; ++ks) {
        int row = wn * 64 + ni * 16 + l16;
        int slot = (ks * 4 + kq) ^ (row & 7);
        breg[ni][ks] = *(const short8*)(pb + row * 128 + slot * 16);
      }
#pragma unroll
    for (int p = 0; p < 4; ++p) {
      short8 areg[2][2];
#pragma unroll
      for (int mi = 0; mi < 2; ++mi)
#pragma unroll
        for (int ks = 0; ks < 2; ++ks) {
          int row = wm * 128 + (p * 2 + mi) * 16 + l16;
          int slot = (ks * 4 + kq) ^ (row & 7);
          areg[mi][ks] = *(const short8*)(pa + row * 128 + slot * 16);
        }
      __builtin_amdgcn_s_setprio(1);
#pragma unroll
      for (int mi = 0; mi < 2; ++mi)
#pragma unroll
        for (int ni = 0; ni < 4; ++ni)
#pragma unroll
          for (int ks = 0; ks < 2; ++ks)
            acc[p * 2 + mi][ni] = __builtin_amdgcn_mfma_f32_16x16x32_bf16(
                areg[mi][ks], breg[ni][ks], acc[p * 2 + mi][ni], 0, 0, 0);
      __builtin_amdgcn_s_setprio(0);
    }
  };

  const int NT = K >> 6;
  STAGE(0, 0);
  for (int t = 0; t < NT - 1; ++t) {
    STAGE((t + 1) << 6, (t + 1) & 1);
    // wait for tile t's 8 loads (tile t+1's 8 remain in flight), then make
    // all waves' staged data visible
    asm volatile("s_waitcnt vmcnt(8)" ::: "memory");
    barrier_fenced();
    COMPUTE(t & 1);
    barrier_fenced();   // all waves done reading buf before it is re-staged
  }
  asm volatile("s_waitcnt vmcnt(0)" ::: "memory");
  barrier_fenced();
  COMPUTE((NT - 1) & 1);

  // --- epilogue ---
#pragma unroll
  for (int mi = 0; mi < 8; ++mi) {
#pragma unroll
    for (int ni = 0; ni < 4; ++ni) {
      int row0 = tm + wm * 128 + mi * 16 + kq * 4;
      int col = tn + wn * 64 + ni * 16 + l16;
#pragma unroll
      for (int r = 0; r < 4; ++r) {
        int row = row0 + r;
        float val = acc[mi][ni][r];
        if (EPI == 0) {
          Cb[(size_t)row * N + col] = f2bf(val);
        } else {
          int bb = row / TIMG;
          int t2 = row - bb * TIMG;
          size_t o = (size_t)(bb * SEQ + t2) * DM + col;
          Cf[o] = resid[o] + val;
        }
      }
    }
  }
}

// ---------------- attention over frames: per (b,s), 16 thr/head ----------------
__global__ __launch_bounds__(256)
void k_attn(const unsigned short* __restrict__ QKV, unsigned short* __restrict__ AOUT) {
  int bs = blockIdx.x;               // 0..3071
  int b = bs / STOK;
  int s = bs - b * STOK;
  int tid = threadIdx.x;
  int h = tid >> 4;
  int part = tid & 15;
  int col = h * HDIM + part * 8;

  float q[4][8], k[4][8], v[4][8];
#pragma unroll
  for (int n = 0; n < 4; ++n) {
    size_t base = (size_t)(b * TIMG + n * STOK + s) * 6144;
    short8 qa = *(const short8*)&QKV[base + col];
    short8 ka = *(const short8*)&QKV[base + 2048 + col];
    short8 va = *(const short8*)&QKV[base + 4096 + col];
#pragma unroll
    for (int j = 0; j < 8; ++j) {
      q[n][j] = bf2f((unsigned short)qa[j]);
      k[n][j] = bf2f((unsigned short)ka[j]);
      v[n][j] = bf2f((unsigned short)va[j]);
    }
  }

  float sc[4][4];
#pragma unroll
  for (int n = 0; n < 4; ++n)
#pragma unroll
    for (int m = 0; m < 4; ++m) {
      float a = 0.f;
#pragma unroll
      for (int j = 0; j < 8; ++j) a += q[n][j] * k[m][j];
#pragma unroll
      for (int mask = 8; mask >= 1; mask >>= 1) a += __shfl_xor(a, mask);
      sc[n][m] = a * 0.08838834764831845f;  // 1/sqrt(128)
    }

  float p[4][4];
#pragma unroll
  for (int n = 0; n < 4; ++n) {
    float mx = fmaxf(fmaxf(sc[n][0], sc[n][1]), fmaxf(sc[n][2], sc[n][3]));
    float sum = 0.f;
#pragma unroll
    for (int m = 0; m < 4; ++m) { p[n][m] = expf(sc[n][m] - mx); sum += p[n][m]; }
    float inv = 1.f / sum;
#pragma unroll
    for (int m = 0; m < 4; ++m) p[n][m] *= inv;
  }

#pragma unroll
  for (int n = 0; n < 4; ++n) {
    float o[8];
#pragma unroll
    for (int j = 0; j < 8; ++j) o[j] = 0.f;
#pragma unroll
    for (int m = 0; m < 4; ++m)
#pragma unroll
      for (int j = 0; j < 8; ++j) o[j] += p[n][m] * v[m][j];
    short8 ov;
#pragma unroll
    for (int j = 0; j < 8; ++j) ov[j] = (short)f2bf(o[j]);
    size_t obase = (size_t)(b * TIMG + n * STOK + s) * DM + col;
    *(short8*)&AOUT[obase] = ov;
  }
}

// ---------------- passthrough for the 48 "other" tokens per batch ----------------
__global__ void k_other(const float4* __restrict__ hid, float4* __restrict__ out) {
  int i = blockIdx.x * 256 + threadIdx.x;  // 0..98303
  int b = i / 24576;                       // 48*2048/4 float4 per batch
  int r = i - b * 24576;
  size_t off = ((size_t)(b * SEQ + TIMG) * DM) / 4 + r;
  out[off] = hid[off];
}

// ---------------- launcher ----------------
extern "C" void kernel_launch(void* const* d_in, const int* in_sizes, int n_in,
                              void* d_out, int out_size, void* d_ws, size_t ws_size,
                              hipStream_t stream) {
  const float* hid   = (const float*)d_in[0];
  const float* Wq    = (const float*)d_in[1];
  const float* Wk    = (const float*)d_in[2];
  const float* Wv    = (const float*)d_in[3];
  const float* Wo    = (const float*)d_in[4];
  const float* gamma = (const float*)d_in[5];
  const float* beta  = (const float*)d_in[6];
  const float* fint  = (const float*)d_in[9];
  float* out = (float*)d_out;

  char* ws = (char*)d_ws;
  float*          enc  = (float*)(ws + 0);                 //    32 KB
  unsigned short* wqkv = (unsigned short*)(ws + 32768);     //  24 MB (6144x2048 bf16)
  unsigned short* wo   = (unsigned short*)(ws + 25198592);  //   8 MB
  unsigned short* X    = (unsigned short*)(ws + 33587200);  //  48 MB (12288x2048 bf16)
  unsigned short* QKV  = (unsigned short*)(ws + 83918848);  // 144 MB (12288x6144 bf16)
  unsigned short* aout = X;  // reuse X's space after GEMM1 (stream-ordered)

  k_enc<<<32, 256, 0, stream>>>(fint, enc);
  k_wconv<<<16384, 256, 0, stream>>>((const float4*)Wq, (const float4*)Wk,
                                     (const float4*)Wv, (const float4*)Wo, wqkv, wo);
  k_ln<<<MTOK, 256, 0, stream>>>(hid, gamma, beta, enc, X);
  // GEMM1: M=12288, N=6144, K=2048 -> grid 24x48 = 1152 blocks (1152%8==0)
  gemm256<0><<<1152, 512, 0, stream>>>(X, wqkv, QKV, nullptr, nullptr,
                                       MTOK, 6144, DM, 24);
  k_attn<<<BATCH * STOK, 256, 0, stream>>>(QKV, aout);
  // GEMM2: M=12288, N=2048, K=2048 -> grid 8x48 = 384 blocks (384%8==0)
  gemm256<1><<<384, 512, 0, stream>>>(aout, wo, nullptr, out, hid,
                                      MTOK, DM, DM, 8);
  k_other<<<384, 256, 0, stream>>>((const float4*)hid, (float4*)out);
}